// Round 1
// baseline (213.752 us; speedup 1.0000x reference)
//
#include <hip/hip_runtime.h>

typedef unsigned short u16;
typedef __bf16 bf16x8 __attribute__((ext_vector_type(8)));
typedef float  f32x4  __attribute__((ext_vector_type(4)));

#define B_   16
#define CIN_ 512
#define COUT_ 512
#define HW_  32
#define KW_  4608   // 9*512, weight row stride in wbf

// ---- helpers ----
__device__ __forceinline__ u16 f2bf(float f) {
    union { float f; unsigned u; } v; v.f = f;
    unsigned r = (v.u + 0x7fffu + ((v.u >> 16) & 1u)) >> 16;
    return (u16)r;
}

// ---------------------------------------------------------------------------
// 1) modulation MLP: s_eff[b][c] = LeakyReLU(LN(w@mod_w.T + mod_b))*scale
// ---------------------------------------------------------------------------
__global__ __launch_bounds__(512) void mod_kernel(
    const float* __restrict__ w, const float* __restrict__ mod_w,
    const float* __restrict__ mod_b, const float* __restrict__ ln_g,
    const float* __restrict__ ln_b, const float* __restrict__ scale,
    float* __restrict__ s_eff)
{
    const int b = blockIdx.x, c = threadIdx.x;
    __shared__ float wsh[512];
    __shared__ float rs[512], rq[512];
    wsh[c] = w[b * 512 + c];
    __syncthreads();
    const float* mwr = mod_w + (size_t)c * 512;
    float acc = 0.f;
#pragma unroll 8
    for (int k = 0; k < 512; ++k) acc = fmaf(wsh[k], mwr[k], acc);
    float s = acc + mod_b[c];
    rs[c] = s; rq[c] = s * s;
    __syncthreads();
    for (int off = 256; off > 0; off >>= 1) {
        if (c < off) { rs[c] += rs[c + off]; rq[c] += rq[c + off]; }
        __syncthreads();
    }
    float mean = rs[0] * (1.f / 512.f);
    float var  = rq[0] * (1.f / 512.f) - mean * mean;
    float sn = (s - mean) * rsqrtf(var + 1e-5f) * ln_g[c] + ln_b[c];
    sn = sn >= 0.f ? sn : 0.2f * sn;
    s_eff[b * 512 + c] = sn * scale[c];
}

// ---------------------------------------------------------------------------
// 2) wsq[o][i] = sum_kk weight^2 ; wbf[o][pos*512+i] = bf16(weight[o][i][pos])
// ---------------------------------------------------------------------------
__global__ __launch_bounds__(256) void wsq_kernel(
    const float* __restrict__ weight, float* __restrict__ wsq, u16* __restrict__ wbf)
{
    int idx = blockIdx.x * 256 + threadIdx.x;      // 0..262143 = cout*512+cin
    int co = idx >> 9, ci = idx & 511;
    const float* wp = weight + (size_t)idx * 9;
    float s = 0.f;
#pragma unroll
    for (int p = 0; p < 9; ++p) {
        float v = wp[p];
        s += v * v;
        wbf[(size_t)co * KW_ + p * 512 + ci] = f2bf(v);
    }
    wsq[idx] = s;
}

// ---------------------------------------------------------------------------
// 3) dsc[b][o] = rsqrt(sum_i s_eff[b][i]^2 * wsq[o][i] + 1e-8)
// ---------------------------------------------------------------------------
__global__ __launch_bounds__(256) void dsc_kernel(
    const float* __restrict__ s_eff, const float* __restrict__ wsq,
    float* __restrict__ dsc)
{
    int gw = (blockIdx.x * 256 + threadIdx.x) >> 6;   // wave id = b*512+cout
    int lane = threadIdx.x & 63;
    int b = gw >> 9, co = gw & 511;
    float a = 0.f;
#pragma unroll
    for (int i = 0; i < 8; ++i) {
        int cin = lane + i * 64;
        float se = s_eff[b * 512 + cin];
        a += se * se * wsq[co * 512 + cin];
    }
    for (int off = 32; off > 0; off >>= 1) a += __shfl_down(a, off);
    if (lane == 0) dsc[gw] = rsqrtf(a + 1e-8f);
}

// ---------------------------------------------------------------------------
// 4) xs[b][h][w][c] (NHWC bf16) = bf16(x[b][c][h][w] * s_eff[b][c])
//    LDS-tiled transpose: block = (b,h), chunks of 64 channels.
// ---------------------------------------------------------------------------
__global__ __launch_bounds__(256) void xs_kernel(
    const float* __restrict__ x, const float* __restrict__ s_eff,
    u16* __restrict__ xs)
{
    const int bh = blockIdx.x;
    const int b = bh >> 5, h = bh & 31;
    __shared__ float tile[64][33];
    for (int c0 = 0; c0 < 512; c0 += 64) {
        if (c0) __syncthreads();
        for (int idx = threadIdx.x; idx < 2048; idx += 256) {
            int c = idx >> 5, ww = idx & 31;
            tile[c][ww] = x[(((size_t)b * 512 + c0 + c) * 32 + h) * 32 + ww]
                          * s_eff[b * 512 + c0 + c];
        }
        __syncthreads();
        for (int idx = threadIdx.x; idx < 2048; idx += 256) {
            int ww = idx >> 6, c = idx & 63;
            xs[((b * 32 + h) * 32 + ww) * 512 + c0 + c] = f2bf(tile[c][ww]);
        }
    }
}

// ---------------------------------------------------------------------------
// 5) conv: implicit-GEMM MFMA bf16.  M=cout(512), N=px(16*1024), K=(pos,cin)
//    block: 512 thr = 8 waves (2M x 4N); tile BM=128 cout x BN=256 px (8 rows)
//    K loop: c0 over 32-cin rounds, 9 taps inside; x staged in LDS [10][34][32]
//    with halo padding; weight a-frags from global (XCD-pinned L2 slice).
// ---------------------------------------------------------------------------
__global__ __launch_bounds__(512, 2) void conv_kernel(
    const u16* __restrict__ wbf,   // [512][4608]  k = pos*512 + cin
    const u16* __restrict__ xs,    // [16][32][32][512] NHWC bf16
    const float* __restrict__ dsc, // [16][512]
    float* __restrict__ out)       // [16][512][32][32]
{
    __shared__ u16 lds[10 * 34 * 32];   // [rr][col][cin] = 21760 B

    const int tid  = threadIdx.x;
    const int lane = tid & 63;
    const int wv   = tid >> 6;          // 0..7
    const int wm   = wv >> 2;           // 0..1  (M waves)
    const int wn   = wv & 3;            // 0..3  (N waves)
    const int l15  = lane & 15;
    const int lg   = lane >> 4;         // 0..3

    const int bx = blockIdx.x;          // 256 blocks
    const int mt = bx & 3;              // cout tile — pinned per XCD (bx&7 rr)
    const int pt = (bx >> 2) & 3;       // row tile (8 rows each)
    const int b  = bx >> 4;             // batch
    const int h0 = pt * 8;

    const u16* xsb = xs + (size_t)b * (32 * 32 * 512);
    const int cobase = mt * 128 + wm * 64 + l15;
    const u16* wb = wbf + (size_t)cobase * KW_ + lg * 8;

    f32x4 acc[4][4] = {};

    // per-thread staging chunks (1360 total = 10*34*4 chunks of 8 cins)
    uint4 pf[3];
    int s_cing[3], s_rr[3], s_col[3];
#pragma unroll
    for (int i = 0; i < 3; ++i) {
        int ch = tid + i * 512;
        s_cing[i] = ch & 3;
        int cr = ch >> 2;
        s_col[i] = cr % 34;
        s_rr[i]  = cr / 34;
    }

    auto prefetch = [&](int c0) {
#pragma unroll
        for (int i = 0; i < 3; ++i) {
            uint4 v = {0u, 0u, 0u, 0u};
            int ch = tid + i * 512;
            if (ch < 1360) {
                int h = h0 + s_rr[i] - 1;
                int w = s_col[i] - 1;
                if ((unsigned)h < 32u && (unsigned)w < 32u)
                    v = *reinterpret_cast<const uint4*>(
                        xsb + (h * 32 + w) * 512 + c0 + s_cing[i] * 8);
            }
            pf[i] = v;
        }
    };
    auto commit = [&]() {
#pragma unroll
        for (int i = 0; i < 3; ++i) {
            int ch = tid + i * 512;
            if (ch < 1360)
                *reinterpret_cast<uint4*>(
                    &lds[(s_rr[i] * 34 + s_col[i]) * 32 + s_cing[i] * 8]) = pf[i];
        }
    };

    prefetch(0);
    for (int c0 = 0; c0 < 512; c0 += 32) {
        __syncthreads();            // prior round's readers done
        commit();
        __syncthreads();
        if (c0 + 32 < 512) prefetch(c0 + 32);   // loads land under MFMA

#pragma unroll
        for (int pos = 0; pos < 9; ++pos) {
            const int kh = pos / 3, kw = pos % 3;
            bf16x8 av[4];
#pragma unroll
            for (int mf = 0; mf < 4; ++mf)
                av[mf] = *reinterpret_cast<const bf16x8*>(
                    wb + (size_t)mf * 16 * KW_ + pos * 512 + c0);
#pragma unroll
            for (int nf = 0; nf < 4; ++nf) {
                int px = wn * 64 + nf * 16 + l15;
                int r = px >> 5, w = px & 31;
                bf16x8 bv = *reinterpret_cast<const bf16x8*>(
                    &lds[((r + kh) * 34 + (w + kw)) * 32 + lg * 8]);
#pragma unroll
                for (int mf = 0; mf < 4; ++mf)
                    acc[mf][nf] = __builtin_amdgcn_mfma_f32_16x16x32_bf16(
                        av[mf], bv, acc[mf][nf], 0, 0, 0);
            }
        }
    }

    // epilogue: scale by dsc and store fp32
#pragma unroll
    for (int mf = 0; mf < 4; ++mf) {
        int co0 = mt * 128 + wm * 64 + mf * 16 + lg * 4;
        float dv[4];
#pragma unroll
        for (int q = 0; q < 4; ++q) dv[q] = dsc[b * 512 + co0 + q];
#pragma unroll
        for (int nf = 0; nf < 4; ++nf) {
            int px = wn * 64 + nf * 16 + l15;
            int r = px >> 5, w = px & 31;
            int h = h0 + r;
#pragma unroll
            for (int q = 0; q < 4; ++q)
                out[(((size_t)b * 512 + co0 + q) * 32 + h) * 32 + w]
                    = acc[mf][nf][q] * dv[q];
        }
    }
}

// ---------------------------------------------------------------------------
extern "C" void kernel_launch(void* const* d_in, const int* in_sizes, int n_in,
                              void* d_out, int out_size, void* d_ws, size_t ws_size,
                              hipStream_t stream) {
    const float* x      = (const float*)d_in[0];
    const float* w      = (const float*)d_in[1];
    const float* mod_w  = (const float*)d_in[2];
    const float* mod_b  = (const float*)d_in[3];
    const float* ln_g   = (const float*)d_in[4];
    const float* ln_b   = (const float*)d_in[5];
    const float* weight = (const float*)d_in[6];
    const float* scale  = (const float*)d_in[7];
    float* out = (float*)d_out;

    char* ws = (char*)d_ws;
    float* s_eff = (float*)(ws);                               // 32 KB
    float* dsc   = (float*)(ws + 32768);                       // 32 KB
    float* wsq   = (float*)(ws + 65536);                       // 1 MB
    u16*   wbf   = (u16*)(ws + 65536 + 1048576);               // 4.5 MB
    u16*   xs    = (u16*)(ws + 65536 + 1048576 + 4718592);     // 16 MB
    if (ws_size < 22609920u) return;   // insufficient scratch -> clean fail

    mod_kernel<<<16, 512, 0, stream>>>(w, mod_w, mod_b, ln_g, ln_b, scale, s_eff);
    wsq_kernel<<<1024, 256, 0, stream>>>(weight, wsq, wbf);
    xs_kernel<<<512, 256, 0, stream>>>(x, s_eff, xs);
    dsc_kernel<<<2048, 256, 0, stream>>>(s_eff, wsq, dsc);
    conv_kernel<<<256, 512, 0, stream>>>(wbf, xs, dsc, out);
}